// Round 3
// baseline (418.442 us; speedup 1.0000x reference)
//
#include <hip/hip_runtime.h>

typedef unsigned short u16;
typedef u16 u16x8 __attribute__((ext_vector_type(8)));
typedef u16 u16x4 __attribute__((ext_vector_type(4)));
typedef float f32x4 __attribute__((ext_vector_type(4)));
typedef __bf16 bf16x8 __attribute__((ext_vector_type(8)));

// SCALE * log2(e): softmax computed in exp2 domain, folded into Q at GEMM1.
#define QSCALE_LOG2E 0.18033688011112042f

__device__ __forceinline__ u16 cvt_bf16(float f) {
  __bf16 h = (__bf16)f;
  return __builtin_bit_cast(u16, h);
}

__device__ __forceinline__ void gl_lds16(const void* g, void* l) {
  __builtin_amdgcn_global_load_lds(
      (const __attribute__((address_space(1))) void*)g,
      (__attribute__((address_space(3))) void*)l, 16, 0, 0);
}

// ---------------- cast fp32 -> bf16, 8 elems/thread ----------------
__global__ __launch_bounds__(256) void cast_f32_bf16(const float* __restrict__ in,
                                                     u16* __restrict__ out) {
  long i = ((long)blockIdx.x * 256 + threadIdx.x) * 8;
  f32x4 a = *(const f32x4*)(in + i);
  f32x4 b = *(const f32x4*)(in + i + 4);
  u16x8 o;
  o[0] = cvt_bf16(a[0]); o[1] = cvt_bf16(a[1]); o[2] = cvt_bf16(a[2]); o[3] = cvt_bf16(a[3]);
  o[4] = cvt_bf16(b[0]); o[5] = cvt_bf16(b[1]); o[6] = cvt_bf16(b[2]); o[7] = cvt_bf16(b[3]);
  *(u16x8*)(out + i) = o;
}

// ---------------- NT GEMM: C = A * B^T  (both row-major [rows][K=1024]) ----
// 128x128 tile, BK=32, 4 waves each owning a 64x64 quadrant (4x4 frags).
// MODE 0: bf16 out into qk [M][2048]; Q cols (bn<1024) pre-scaled by
//         SCALE*log2e; cols>=2048 go TRANSPOSED into Vt[bh*64+d][2048].
// MODE 1: fp32 out [M][1024] + bias.
template<int MODE>
__global__ __launch_bounds__(256) void gemm_nt(
    const u16* __restrict__ A, const u16* __restrict__ Bw,
    u16* __restrict__ Cb, u16* __restrict__ Vt,
    float* __restrict__ Cf, const float* __restrict__ bias) {
  constexpr int K = 1024;
  __shared__ __align__(16) u16 sA[128 * 32];
  __shared__ __align__(16) u16 sB[128 * 32];
  const int t = threadIdx.x;
  const int w = t >> 6, l = t & 63;
  const int fr = l & 15, fg = l >> 4;
  const int bm = blockIdx.y * 128, bn = blockIdx.x * 128;
  const int wr = (w >> 1) << 6, wc = (w & 1) << 6;

  f32x4 acc[4][4] = {};

  const int tr = t >> 2, tc = (t & 3) * 8;  // staging: row t>>2, 8-elem chunk
  const u16* gA0 = A + (long)(bm + tr) * K + tc;
  const u16* gB0 = Bw + (long)(bn + tr) * K + tc;
  char* sAc = (char*)sA; char* sBc = (char*)sB;
  const int wb = w * 1024;  // wave-uniform LDS byte base

  for (int k0 = 0; k0 < K; k0 += 32) {
    gl_lds16(gA0 + k0,                 sAc + wb);
    gl_lds16(gA0 + (long)64 * K + k0,  sAc + 4096 + wb);
    gl_lds16(gB0 + k0,                 sBc + wb);
    gl_lds16(gB0 + (long)64 * K + k0,  sBc + 4096 + wb);
    __syncthreads();
    bf16x8 af[4], bf[4];
#pragma unroll
    for (int m = 0; m < 4; ++m)
      af[m] = *(const bf16x8*)&sA[(wr + m * 16 + fr) * 32 + fg * 8];
#pragma unroll
    for (int n = 0; n < 4; ++n)
      bf[n] = *(const bf16x8*)&sB[(wc + n * 16 + fr) * 32 + fg * 8];
#pragma unroll
    for (int m = 0; m < 4; ++m) {
#pragma unroll
      for (int n = 0; n < 4; ++n)
        acc[m][n] = __builtin_amdgcn_mfma_f32_16x16x32_bf16(af[m], bf[n], acc[m][n], 0, 0, 0);
    }
    __syncthreads();
  }

  const float cmul = (MODE == 0 && bn < 1024) ? QSCALE_LOG2E : 1.0f;
#pragma unroll
  for (int m = 0; m < 4; ++m) {
    const int grow = bm + wr + m * 16 + fg * 4;  // 4 consecutive rows
#pragma unroll
    for (int n = 0; n < 4; ++n) {
      const int gcol = bn + wc + n * 16 + fr;
      if (MODE == 1) {
        float bv = bias[gcol];
#pragma unroll
        for (int r = 0; r < 4; ++r)
          Cf[(long)(grow + r) * 1024 + gcol] = acc[m][n][r] + bv;
      } else {
        if (bn < 2048) {
#pragma unroll
          for (int r = 0; r < 4; ++r)
            Cb[(long)(grow + r) * 2048 + gcol] = cvt_bf16(acc[m][n][r] * cmul);
        } else {
          const int d = gcol - 2048;           // 0..1023 -> (h, dl)
          const int bb = grow >> 11, nn = grow & 2047;
          u16x4 pk;
#pragma unroll
          for (int r = 0; r < 4; ++r) pk[r] = cvt_bf16(acc[m][n][r]);
          *(u16x4*)&Vt[((long)(bb * 16 + (d >> 6)) * 64 + (d & 63)) * 2048 + nn] = pk;
        }
      }
    }
  }
}

// ---------------- flash attention ----------------
// grid (32 q-tiles, 64 bh). 4 waves x 16 q-rows. KVBLK=64.
// Double-buffered K/V staging (prefetch next tile before compute, one
// barrier per tile). Softmax in exp2 domain (scale pre-folded into Q).
// qk: [B*N][2048] (Q cols 0..1023 scaled, K cols 1024..2047);
// vt: [bh*64+d][2048].
__global__ __launch_bounds__(256) void attn_fused(
    const u16* __restrict__ qk, const u16* __restrict__ vt,
    u16* __restrict__ ao) {
  const int t = threadIdx.x;
  const int w = t >> 6, l = t & 63;
  const int fr = l & 15, fg = l >> 4;
  const int q0 = blockIdx.x * 64;
  const int bh = blockIdx.y, b = bh >> 4, h = bh & 15;

  __shared__ __align__(16) u16 sK[2][4096];   // [buf][kk 2][kv 64][d-chunk 32]
  __shared__ __align__(16) u16 sV[2][4096];   // [buf][kc 2][d 64][kv-chunk 32]
  __shared__ __align__(16) u16 sP[4][16 * 72];  // per-wave P [16 q][72]

  // Q fragments (hoisted): rows q0+w*16+fr, d = fg*8+32*kk + j
  bf16x8 qf[2];
  {
    const u16* qb = qk + (long)(b * 2048 + q0 + w * 16 + fr) * 2048 + h * 64 + fg * 8;
    qf[0] = *(const bf16x8*)qb;
    qf[1] = *(const bf16x8*)(qb + 32);
  }

  f32x4 acc_o[4] = {};
  float mrow[4], lrow[4];
#pragma unroll
  for (int r = 0; r < 4; ++r) { mrow[r] = -__builtin_inff(); lrow[r] = 0.f; }

  const u16* gK = qk + (long)(b * 2048 + (t >> 2)) * 2048 + 1024 + h * 64 + (t & 3) * 8;
  const u16* gV = vt + (long)(bh * 64 + (t >> 2)) * 2048 + (t & 3) * 8;
  char* sKc = (char*)sK; char* sVc = (char*)sV;
  const int wb = w * 1024;
  u16* sPw = &sP[w][0];

  auto STAGE = [&](int buf, int kv0) {
    char* kb = sKc + buf * 8192 + wb;
    char* vb = sVc + buf * 8192 + wb;
    gl_lds16(gK + (long)kv0 * 2048,      kb);
    gl_lds16(gK + (long)kv0 * 2048 + 32, kb + 4096);
    gl_lds16(gV + kv0,                   vb);
    gl_lds16(gV + kv0 + 32,              vb + 4096);
  };

  STAGE(0, 0);
  __syncthreads();  // drains vmcnt(0): tile 0 staged
  int cur = 0;

  for (int ti = 0; ti < 32; ++ti) {
    if (ti < 31) STAGE(cur ^ 1, (ti + 1) * 64);  // prefetch next tile

    const u16* sKb = &sK[cur][0];
    const u16* sVb = &sV[cur][0];

    // S' = (Q*c) K^T in exp2 domain (16 x 64 per wave), fp32 acc
    f32x4 s[4] = {};
#pragma unroll
    for (int kk = 0; kk < 2; ++kk) {
#pragma unroll
      for (int t2 = 0; t2 < 4; ++t2) {
        bf16x8 kf = *(const bf16x8*)&sKb[kk * 2048 + (t2 * 16 + fr) * 32 + fg * 8];
        s[t2] = __builtin_amdgcn_mfma_f32_16x16x32_bf16(qf[kk], kf, s[t2], 0, 0, 0);
      }
    }

    // online softmax (exp2 domain). Row r of this wave = fg*4 + r.
    float nm[4];
#pragma unroll
    for (int r = 0; r < 4; ++r) {
      float v = fmaxf(fmaxf(s[0][r], s[1][r]), fmaxf(s[2][r], s[3][r]));
      v = fmaxf(v, __shfl_xor(v, 1));
      v = fmaxf(v, __shfl_xor(v, 2));
      v = fmaxf(v, __shfl_xor(v, 4));
      v = fmaxf(v, __shfl_xor(v, 8));
      nm[r] = v;
    }
    float g = fmaxf(fmaxf(nm[0] - mrow[0], nm[1] - mrow[1]),
                    fmaxf(nm[2] - mrow[2], nm[3] - mrow[3]));
    if (!__all(g <= 8.0f)) {   // T13 defer-rescale: skip when growth small
#pragma unroll
      for (int r = 0; r < 4; ++r) {
        float mn = fmaxf(mrow[r], nm[r]);
        float al = __builtin_amdgcn_exp2f(mrow[r] - mn);
        mrow[r] = mn;
        lrow[r] *= al;
#pragma unroll
        for (int tt = 0; tt < 4; ++tt) acc_o[tt][r] *= al;
      }
    }
#pragma unroll
    for (int r = 0; r < 4; ++r) {
      float rsum = 0.f;
#pragma unroll
      for (int t2 = 0; t2 < 4; ++t2) {
        float p = __builtin_amdgcn_exp2f(s[t2][r] - mrow[r]);
        s[t2][r] = p;
        rsum += p;
      }
      rsum += __shfl_xor(rsum, 1);
      rsum += __shfl_xor(rsum, 2);
      rsum += __shfl_xor(rsum, 4);
      rsum += __shfl_xor(rsum, 8);
      lrow[r] += rsum;
    }

    // P -> per-wave LDS (transpose via LDS; same-wave, no barrier needed)
#pragma unroll
    for (int t2 = 0; t2 < 4; ++t2) {
#pragma unroll
      for (int r = 0; r < 4; ++r)
        sPw[(fg * 4 + r) * 72 + t2 * 16 + fr] = cvt_bf16(s[t2][r]);
    }

    // O += P * V
#pragma unroll
    for (int kc = 0; kc < 2; ++kc) {
      bf16x8 pf = *(const bf16x8*)&sPw[fr * 72 + kc * 32 + fg * 8];
#pragma unroll
      for (int tt = 0; tt < 4; ++tt) {
        bf16x8 vf = *(const bf16x8*)&sVb[kc * 2048 + (tt * 16 + fr) * 32 + fg * 8];
        acc_o[tt] = __builtin_amdgcn_mfma_f32_16x16x32_bf16(pf, vf, acc_o[tt], 0, 0, 0);
      }
    }
    __syncthreads();  // next-tile stage complete + all waves done with cur
    cur ^= 1;
  }

  u16* ob = ao + (long)(b * 2048 + q0 + w * 16) * 1024 + h * 64;
#pragma unroll
  for (int r = 0; r < 4; ++r) {
    float inv = 1.f / lrow[r];
#pragma unroll
    for (int tt = 0; tt < 4; ++tt)
      ob[(long)(fg * 4 + r) * 1024 + tt * 16 + fr] = cvt_bf16(acc_o[tt][r] * inv);
  }
}

extern "C" void kernel_launch(void* const* d_in, const int* in_sizes, int n_in,
                              void* d_out, int out_size, void* d_ws, size_t ws_size,
                              hipStream_t stream) {
  const float* x     = (const float*)d_in[0];   // [4,2048,1024]
  const float* wqkv  = (const float*)d_in[1];   // [3072,1024]
  const float* wproj = (const float*)d_in[2];   // [1024,1024]
  const float* bproj = (const float*)d_in[3];   // [1024]
  float* out = (float*)d_out;

  u16* ws    = (u16*)d_ws;
  u16* xb    = ws;                    // 8388608  : x bf16 (dead after gemm1)
  u16* wqkvb = xb + 8388608;          // 3145728  : w_qkv bf16
  u16* wpb   = wqkvb + 3145728;       // 1048576  : w_proj bf16
  u16* qkb   = wpb + 1048576;         // 16777216 : [B*N][2048] Q|K bf16
  u16* vtb   = qkb + 16777216;        // 8388608  : [bh*64+d][2048] V^T bf16
  u16* aob   = xb;                    // aliases xb (x dead before attn writes)
  // peak 37748736 u16 = 75.5 MB

  cast_f32_bf16<<<4096, 256, 0, stream>>>(x, xb);
  cast_f32_bf16<<<1536, 256, 0, stream>>>(wqkv, wqkvb);
  cast_f32_bf16<<<512, 256, 0, stream>>>(wproj, wpb);

  gemm_nt<0><<<dim3(24, 64), 256, 0, stream>>>(xb, wqkvb, qkb, vtb, nullptr, nullptr);
  attn_fused<<<dim3(32, 64), 256, 0, stream>>>(qkb, vtb, aob);
  gemm_nt<1><<<dim3(8, 64), 256, 0, stream>>>(aob, wpb, nullptr, nullptr, out, bproj);
}

// Round 5
// 278.627 us; speedup vs baseline: 1.5018x; 1.5018x over previous
//
#include <hip/hip_runtime.h>

typedef unsigned short u16;
typedef u16 u16x8 __attribute__((ext_vector_type(8)));
typedef u16 u16x4 __attribute__((ext_vector_type(4)));
typedef unsigned u32x4 __attribute__((ext_vector_type(4)));
typedef float f32x4 __attribute__((ext_vector_type(4)));
typedef float f32x16 __attribute__((ext_vector_type(16)));
typedef __bf16 bf16x8 __attribute__((ext_vector_type(8)));

// SCALE * log2(e): softmax computed in exp2 domain, folded into Q at GEMM1.
#define QSCALE_LOG2E 0.18033688011112042f

__device__ __forceinline__ u16 cvt_bf16(float f) {
  __bf16 h = (__bf16)f;
  return __builtin_bit_cast(u16, h);
}

__device__ __forceinline__ void gl_lds16(const void* g, void* l) {
  __builtin_amdgcn_global_load_lds(
      (const __attribute__((address_space(1))) void*)g,
      (__attribute__((address_space(3))) void*)l, 16, 0, 0);
}

// ---------------- cast fp32 -> bf16, 8 elems/thread ----------------
__global__ __launch_bounds__(256) void cast_f32_bf16(const float* __restrict__ in,
                                                     u16* __restrict__ out) {
  long i = ((long)blockIdx.x * 256 + threadIdx.x) * 8;
  f32x4 a = *(const f32x4*)(in + i);
  f32x4 b = *(const f32x4*)(in + i + 4);
  u16x8 o;
  o[0] = cvt_bf16(a[0]); o[1] = cvt_bf16(a[1]); o[2] = cvt_bf16(a[2]); o[3] = cvt_bf16(a[3]);
  o[4] = cvt_bf16(b[0]); o[5] = cvt_bf16(b[1]); o[6] = cvt_bf16(b[2]); o[7] = cvt_bf16(b[3]);
  *(u16x8*)(out + i) = o;
}

// ---------------- NT GEMM: C = A * B^T  (both row-major [rows][K=1024]) ----
// 128x128 tile, BK=32, 4 waves each owning a 64x64 quadrant (4x4 frags).
// MODE 0: bf16 out into qk [M][2048]; Q cols (bn<1024) pre-scaled by
//         SCALE*log2e; cols>=2048 go TRANSPOSED into Vt[bh*64+d][2048].
// MODE 1: fp32 out [M][1024] + bias.
template<int MODE>
__global__ __launch_bounds__(256) void gemm_nt(
    const u16* __restrict__ A, const u16* __restrict__ Bw,
    u16* __restrict__ Cb, u16* __restrict__ Vt,
    float* __restrict__ Cf, const float* __restrict__ bias) {
  constexpr int K = 1024;
  __shared__ __align__(16) u16 sA[128 * 32];
  __shared__ __align__(16) u16 sB[128 * 32];
  const int t = threadIdx.x;
  const int w = t >> 6, l = t & 63;
  const int fr = l & 15, fg = l >> 4;
  const int bm = blockIdx.y * 128, bn = blockIdx.x * 128;
  const int wr = (w >> 1) << 6, wc = (w & 1) << 6;

  f32x4 acc[4][4] = {};

  const int tr = t >> 2, tc = (t & 3) * 8;  // staging: row t>>2, 8-elem chunk
  const u16* gA0 = A + (long)(bm + tr) * K + tc;
  const u16* gB0 = Bw + (long)(bn + tr) * K + tc;
  char* sAc = (char*)sA; char* sBc = (char*)sB;
  const int wb = w * 1024;  // wave-uniform LDS byte base

  for (int k0 = 0; k0 < K; k0 += 32) {
    gl_lds16(gA0 + k0,                 sAc + wb);
    gl_lds16(gA0 + (long)64 * K + k0,  sAc + 4096 + wb);
    gl_lds16(gB0 + k0,                 sBc + wb);
    gl_lds16(gB0 + (long)64 * K + k0,  sBc + 4096 + wb);
    __syncthreads();
    bf16x8 af[4], bf[4];
#pragma unroll
    for (int m = 0; m < 4; ++m)
      af[m] = *(const bf16x8*)&sA[(wr + m * 16 + fr) * 32 + fg * 8];
#pragma unroll
    for (int n = 0; n < 4; ++n)
      bf[n] = *(const bf16x8*)&sB[(wc + n * 16 + fr) * 32 + fg * 8];
#pragma unroll
    for (int m = 0; m < 4; ++m) {
#pragma unroll
      for (int n = 0; n < 4; ++n)
        acc[m][n] = __builtin_amdgcn_mfma_f32_16x16x32_bf16(af[m], bf[n], acc[m][n], 0, 0, 0);
    }
    __syncthreads();
  }

  const float cmul = (MODE == 0 && bn < 1024) ? QSCALE_LOG2E : 1.0f;
#pragma unroll
  for (int m = 0; m < 4; ++m) {
    const int grow = bm + wr + m * 16 + fg * 4;  // 4 consecutive rows
#pragma unroll
    for (int n = 0; n < 4; ++n) {
      const int gcol = bn + wc + n * 16 + fr;
      if (MODE == 1) {
        float bv = bias[gcol];
#pragma unroll
        for (int r = 0; r < 4; ++r)
          Cf[(long)(grow + r) * 1024 + gcol] = acc[m][n][r] + bv;
      } else {
        if (bn < 2048) {
#pragma unroll
          for (int r = 0; r < 4; ++r)
            Cb[(long)(grow + r) * 2048 + gcol] = cvt_bf16(acc[m][n][r] * cmul);
        } else {
          const int d = gcol - 2048;           // 0..1023 -> (h, dl)
          const int bb = grow >> 11, nn = grow & 2047;
          u16x4 pk;
#pragma unroll
          for (int r = 0; r < 4; ++r) pk[r] = cvt_bf16(acc[m][n][r]);
          *(u16x4*)&Vt[((long)(bb * 16 + (d >> 6)) * 64 + (d & 63)) * 2048 + nn] = pk;
        }
      }
    }
  }
}

// ---------------- flash attention: swapped-QK^T, in-register P ----------
// 512 blocks x 512 threads. 8 waves x 32 q-rows (block = 256 q). KVBLK=64.
// S^T = mfma_32x32x16(K, Q): lane owns q = lane&31; kv spread over regs
// (kv = (reg&3)+8*(reg>>2)+4*hi + 32*kt). Softmax lane-local + one
// shfl_xor(32). P -> bf16 via v_cvt_pk_bf16_f32 + v_permlane32_swap_b32
// (pairs (W_i, W_{i+2})), feeding PV A-frags in-register.
// K/V LDS [64][64] bf16, XOR-swizzled (chunk ^= row&7) via pre-swizzled
// global_load_lds source; reads apply the same XOR.
__global__ __launch_bounds__(512, 4) void attn_fused(
    const u16* __restrict__ qk, const u16* __restrict__ vt,
    u16* __restrict__ ao) {
  const int t = threadIdx.x;
  const int w = t >> 6, l = t & 63;
  const int hi = l >> 5, ql = l & 31;
  const int bi = blockIdx.x;
  // XCD-grouped decode: XCD (bi&7) hosts bh in {8*(bi&7) .. +7}
  const int bh = (bi & 7) * 8 + ((bi >> 3) & 7);
  const int qt = bi >> 6;                 // 0..7
  const int b = bh >> 4, h = bh & 15;
  const int qbase = qt * 256 + w * 32;

  __shared__ __align__(16) u16 sK[2][4096];   // [buf][64 kv][64 d] swizzled
  __shared__ __align__(16) u16 sV[2][4096];   // [buf][64 d][64 kv] swizzled
  __shared__ float sRed[8][32];               // per-wave broadcast row

  // Q frags (B-operand): lane holds q=qbase+ql, k-chunk hi*8, d = c*16+hi*8+j
  bf16x8 qf[4];
  {
    const u16* qb = qk + (long)(b * 2048 + qbase + ql) * 2048 + h * 64 + hi * 8;
#pragma unroll
    for (int c = 0; c < 4; ++c) qf[c] = *(const bf16x8*)(qb + c * 16);
  }

  // staging source (pre-swizzled): wave w stages rows w*8..w*8+7
  const int srow = w * 8 + (l >> 3);
  const int schunk = (l & 7) ^ (l >> 3);
  const u16* gKs = qk + (long)(b * 2048 + srow) * 2048 + 1024 + h * 64 + schunk * 8;
  const u16* gVs = vt + (long)(bh * 64 + srow) * 2048 + schunk * 8;
  char* sKc = (char*)sK; char* sVc = (char*)sV;
  const int wb = w * 1024;

  auto STAGE = [&](int buf, int kv0) {
    gl_lds16(gKs + (long)kv0 * 2048, sKc + buf * 8192 + wb);
    gl_lds16(gVs + kv0,              sVc + buf * 8192 + wb);
  };

  f32x16 acc0 = {}, acc1 = {};
  float mrow = -__builtin_inff(), lrow = 0.f;

  STAGE(0, 0);
  __syncthreads();
  int cur = 0;

  for (int ti = 0; ti < 32; ++ti) {
    if (ti < 31) STAGE(cur ^ 1, (ti + 1) * 64);

    // ---- S^T = K * Q^T (two 32x32 tiles over kv) ----
    f32x16 s0 = {}, s1 = {};
#pragma unroll
    for (int c = 0; c < 4; ++c) {
      bf16x8 kf = *(const bf16x8*)&sK[cur][(0 * 32 + ql) * 64 + (((2 * c + hi) ^ (l & 7)) * 8)];
      s0 = __builtin_amdgcn_mfma_f32_32x32x16_bf16(kf, qf[c], s0, 0, 0, 0);
    }
#pragma unroll
    for (int c = 0; c < 4; ++c) {
      bf16x8 kf = *(const bf16x8*)&sK[cur][(1 * 32 + ql) * 64 + (((2 * c + hi) ^ (l & 7)) * 8)];
      s1 = __builtin_amdgcn_mfma_f32_32x32x16_bf16(kf, qf[c], s1, 0, 0, 0);
    }

    // ---- online softmax (exp2 domain), lane-local over 32 regs ----
    float mloc = s0[0];
#pragma unroll
    for (int r = 1; r < 16; ++r) mloc = fmaxf(mloc, s0[r]);
#pragma unroll
    for (int r = 0; r < 16; ++r) mloc = fmaxf(mloc, s1[r]);
    mloc = fmaxf(mloc, __shfl_xor(mloc, 32));
    float nm = fmaxf(mrow, mloc);
    if (!__all(nm - mrow <= 8.0f)) {          // T13 defer-rescale
      float al = __builtin_amdgcn_exp2f(mrow - nm);
      lrow *= al;
      mrow = nm;
      if (l < 32) sRed[w][ql] = al;
#pragma unroll
      for (int r = 0; r < 16; ++r) {
        float a2 = sRed[w][(r & 3) + 8 * (r >> 2) + 4 * hi];
        acc0[r] *= a2;
        acc1[r] *= a2;
      }
    }
    float ls = 0.f;
#pragma unroll
    for (int r = 0; r < 16; ++r) { float p = __builtin_amdgcn_exp2f(s0[r] - mrow); s0[r] = p; ls += p; }
#pragma unroll
    for (int r = 0; r < 16; ++r) { float p = __builtin_amdgcn_exp2f(s1[r] - mrow); s1[r] = p; ls += p; }
    ls += __shfl_xor(ls, 32);
    lrow += ls;

    // ---- P -> bf16 A-frags in-register (cvt_pk + permlane32_swap) ----
    bf16x8 pa[2][2];
    {
      unsigned W[8];
#pragma unroll
      for (int ii = 0; ii < 8; ++ii)
        asm("v_cvt_pk_bf16_f32 %0, %1, %2" : "=v"(W[ii]) : "v"(s0[2 * ii]), "v"(s0[2 * ii + 1]));
      asm("v_permlane32_swap_b32 %0, %1" : "+v"(W[0]), "+v"(W[2]));
      asm("v_permlane32_swap_b32 %0, %1" : "+v"(W[1]), "+v"(W[3]));
      asm("v_permlane32_swap_b32 %0, %1" : "+v"(W[4]), "+v"(W[6]));
      asm("v_permlane32_swap_b32 %0, %1" : "+v"(W[5]), "+v"(W[7]));
      u32x4 f0 = {W[0], W[1], W[2], W[3]}, f1 = {W[4], W[5], W[6], W[7]};
      pa[0][0] = __builtin_bit_cast(bf16x8, f0);
      pa[0][1] = __builtin_bit_cast(bf16x8, f1);
    }
    {
      unsigned W[8];
#pragma unroll
      for (int ii = 0; ii < 8; ++ii)
        asm("v_cvt_pk_bf16_f32 %0, %1, %2" : "=v"(W[ii]) : "v"(s1[2 * ii]), "v"(s1[2 * ii + 1]));
      asm("v_permlane32_swap_b32 %0, %1" : "+v"(W[0]), "+v"(W[2]));
      asm("v_permlane32_swap_b32 %0, %1" : "+v"(W[1]), "+v"(W[3]));
      asm("v_permlane32_swap_b32 %0, %1" : "+v"(W[4]), "+v"(W[6]));
      asm("v_permlane32_swap_b32 %0, %1" : "+v"(W[5]), "+v"(W[7]));
      u32x4 f0 = {W[0], W[1], W[2], W[3]}, f1 = {W[4], W[5], W[6], W[7]};
      pa[1][0] = __builtin_bit_cast(bf16x8, f0);
      pa[1][1] = __builtin_bit_cast(bf16x8, f1);
    }

    // ---- O += P * V ----
#pragma unroll
    for (int kt = 0; kt < 2; ++kt) {
#pragma unroll
      for (int kc = 0; kc < 2; ++kc) {
        bf16x8 v0 = *(const bf16x8*)&sV[cur][(0 * 32 + ql) * 64 + (((4 * kt + 2 * kc + hi) ^ (l & 7)) * 8)];
        acc0 = __builtin_amdgcn_mfma_f32_32x32x16_bf16(pa[kt][kc], v0, acc0, 0, 0, 0);
        bf16x8 v1 = *(const bf16x8*)&sV[cur][(1 * 32 + ql) * 64 + (((4 * kt + 2 * kc + hi) ^ (l & 7)) * 8)];
        acc1 = __builtin_amdgcn_mfma_f32_32x32x16_bf16(pa[kt][kc], v1, acc1, 0, 0, 0);
      }
    }
    __syncthreads();   // drains vmcnt(0): next tile staged; all done with cur
    cur ^= 1;
  }

  // ---- epilogue: O[q][d] = acc/l ----
  if (l < 32) sRed[w][ql] = 1.0f / lrow;
  __builtin_amdgcn_s_waitcnt(0);  // lgkmcnt drain before cross-lane read; benign
#pragma unroll
  for (int r = 0; r < 16; ++r) {
    const int qr = (r & 3) + 8 * (r >> 2) + 4 * hi;
    const float inv = sRed[w][qr];
    u16* ob = ao + (long)(b * 2048 + qbase + qr) * 1024 + h * 64 + ql;
    ob[0]  = cvt_bf16(acc0[r] * inv);
    ob[32] = cvt_bf16(acc1[r] * inv);
  }
}

extern "C" void kernel_launch(void* const* d_in, const int* in_sizes, int n_in,
                              void* d_out, int out_size, void* d_ws, size_t ws_size,
                              hipStream_t stream) {
  const float* x     = (const float*)d_in[0];   // [4,2048,1024]
  const float* wqkv  = (const float*)d_in[1];   // [3072,1024]
  const float* wproj = (const float*)d_in[2];   // [1024,1024]
  const float* bproj = (const float*)d_in[3];   // [1024]
  float* out = (float*)d_out;

  u16* ws    = (u16*)d_ws;
  u16* xb    = ws;                    // 8388608  : x bf16 (dead after gemm1)
  u16* wqkvb = xb + 8388608;          // 3145728  : w_qkv bf16
  u16* wpb   = wqkvb + 3145728;       // 1048576  : w_proj bf16
  u16* qkb   = wpb + 1048576;         // 16777216 : [B*N][2048] Q|K bf16
  u16* vtb   = qkb + 16777216;        // 8388608  : [bh*64+d][2048] V^T bf16
  u16* aob   = xb;                    // aliases xb (x dead before attn writes)
  // peak 37748736 u16 = 75.5 MB

  cast_f32_bf16<<<4096, 256, 0, stream>>>(x, xb);
  cast_f32_bf16<<<1536, 256, 0, stream>>>(wqkv, wqkvb);
  cast_f32_bf16<<<512, 256, 0, stream>>>(wproj, wpb);

  gemm_nt<0><<<dim3(24, 64), 256, 0, stream>>>(xb, wqkvb, qkb, vtb, nullptr, nullptr);
  attn_fused<<<512, 512, 0, stream>>>(qkb, vtb, aob);
  gemm_nt<1><<<dim3(8, 64), 256, 0, stream>>>(aob, wpb, nullptr, nullptr, out, bproj);
}